// Round 1
// baseline (45.282 us; speedup 1.0000x reference)
//
#include <hip/hip_runtime.h>
#include <math.h>

// Problem constants (from setup_inputs)
#define D 1024
#define M 8192
#define N 16384
#define CHUNKS 128                 // blocks for embed column reduction
#define ROWS_PER_CHUNK (M / CHUNKS) // 64
#define NB 2048                    // blocks for input pass
#define EPS 1e-8f

// ws layout (bytes):
//   [0, NB*8)                      : double partials
//   [NB*8, NB*8 + D*4)             : float coef[D]
//   then pS[CHUNKS*D] floats, pQ[CHUNKS*D] floats

__global__ __launch_bounds__(256) void colsum_kernel(const float* __restrict__ embed,
                                                     float* __restrict__ pS,
                                                     float* __restrict__ pQ) {
    const int chunk = blockIdx.x;
    const int t = threadIdx.x;            // 0..255
    const int col = t * 4;                // 4 columns per thread
    const size_t r0 = (size_t)chunk * ROWS_PER_CHUNK;
    float4 s = make_float4(0.f, 0.f, 0.f, 0.f);
    float4 q = make_float4(0.f, 0.f, 0.f, 0.f);
    for (int r = 0; r < ROWS_PER_CHUNK; ++r) {
        float4 v = *reinterpret_cast<const float4*>(embed + (r0 + r) * D + col);
        s.x += v.x; s.y += v.y; s.z += v.z; s.w += v.w;
        q.x += v.x * v.x; q.y += v.y * v.y; q.z += v.z * v.z; q.w += v.w * v.w;
    }
    *reinterpret_cast<float4*>(pS + (size_t)chunk * D + col) = s;
    *reinterpret_cast<float4*>(pQ + (size_t)chunk * D + col) = q;
}

__global__ __launch_bounds__(256) void coef_kernel(const float* __restrict__ pS,
                                                   const float* __restrict__ pQ,
                                                   float* __restrict__ coef) {
    const int d = blockIdx.x * 256 + threadIdx.x;   // 4 blocks x 256 = 1024
    float s = 0.f, q = 0.f;
    for (int c = 0; c < CHUNKS; ++c) {
        s += pS[(size_t)c * D + d];
        q += pQ[(size_t)c * D + d];
    }
    float n2 = sqrtf(q);
    coef[d] = s / fmaxf(n2, EPS);
}

__global__ __launch_bounds__(256) void dotsum_kernel(const float* __restrict__ input,
                                                     const float* __restrict__ coef,
                                                     double* __restrict__ partials) {
    __shared__ float scoef[D];
    for (int i = threadIdx.x; i < D; i += 256) scoef[i] = coef[i];
    __syncthreads();

    const float sqrtM = 90.50966799187809f;  // f32 sqrt(8192), rounds to same f32 as ref
    const size_t total4 = (size_t)N * D / 4;
    double acc = 0.0;
    for (size_t i = (size_t)blockIdx.x * 256 + threadIdx.x; i < total4;
         i += (size_t)gridDim.x * 256) {
        float4 v = reinterpret_cast<const float4*>(input)[i];
        int dbase = (int)((i * 4) & (D - 1));
        float4 c = *reinterpret_cast<const float4*>(&scoef[dbase]);
        float t0 = (v.x * c.x) / fmaxf(sqrtM * fabsf(v.x), EPS);
        float t1 = (v.y * c.y) / fmaxf(sqrtM * fabsf(v.y), EPS);
        float t2 = (v.z * c.z) / fmaxf(sqrtM * fabsf(v.z), EPS);
        float t3 = (v.w * c.w) / fmaxf(sqrtM * fabsf(v.w), EPS);
        acc += (double)t0 + (double)t1 + (double)t2 + (double)t3;
    }

    // wave (64-lane) shuffle reduce, then LDS across 4 waves
    for (int off = 32; off > 0; off >>= 1) acc += __shfl_down(acc, off);
    __shared__ double wsum[4];
    const int lane = threadIdx.x & 63;
    const int wid = threadIdx.x >> 6;
    if (lane == 0) wsum[wid] = acc;
    __syncthreads();
    if (threadIdx.x == 0)
        partials[blockIdx.x] = wsum[0] + wsum[1] + wsum[2] + wsum[3];
}

__global__ __launch_bounds__(256) void final_kernel(const double* __restrict__ partials,
                                                    float* __restrict__ out) {
    double acc = 0.0;
    for (int i = threadIdx.x; i < NB; i += 256) acc += partials[i];  // fixed order
    for (int off = 32; off > 0; off >>= 1) acc += __shfl_down(acc, off);
    __shared__ double wsum[4];
    const int lane = threadIdx.x & 63;
    const int wid = threadIdx.x >> 6;
    if (lane == 0) wsum[wid] = acc;
    __syncthreads();
    if (threadIdx.x == 0)
        out[0] = (float)(wsum[0] + wsum[1] + wsum[2] + wsum[3]);
}

extern "C" void kernel_launch(void* const* d_in, const int* in_sizes, int n_in,
                              void* d_out, int out_size, void* d_ws, size_t ws_size,
                              hipStream_t stream) {
    const float* input = (const float*)d_in[0];   // [N, D]
    const float* embed = (const float*)d_in[1];   // [M, D]
    float* out = (float*)d_out;

    char* ws = (char*)d_ws;
    double* partials = (double*)ws;                         // NB doubles
    float* coef = (float*)(ws + NB * sizeof(double));       // D floats
    float* pS = (float*)(ws + NB * sizeof(double) + D * sizeof(float));
    float* pQ = pS + (size_t)CHUNKS * D;

    colsum_kernel<<<CHUNKS, 256, 0, stream>>>(embed, pS, pQ);
    coef_kernel<<<D / 256, 256, 0, stream>>>(pS, pQ, coef);
    dotsum_kernel<<<NB, 256, 0, stream>>>(input, coef, partials);
    final_kernel<<<1, 256, 0, stream>>>(partials, out);
}

// Round 2
// 38.273 us; speedup vs baseline: 1.1831x; 1.1831x over previous
//
#include <hip/hip_runtime.h>
#include <math.h>

// Problem constants (from setup_inputs)
#define D 1024
#define M 8192
#define N 16384
#define EPS 1e-8

#define IN_BLOCKS 512               // input sign-count blocks, 32 rows each
#define EM_BLOCKS 256               // embed sum/sumsq blocks, 32 rows each
#define ROWS 32
#define RED_BLOCKS 64               // reduce kernel: 16 columns per block

// ws layout (floats / doubles):
//   pSign [IN_BLOCKS][D] f32   (2 MB)
//   pS    [EM_BLOCKS][D] f32   (1 MB)
//   pQ    [EM_BLOCKS][D] f32   (1 MB)
//   blockRes [RED_BLOCKS] f64

// K1: dual-role streaming kernel. Blocks 0..511 -> input sign counts,
// blocks 512..767 -> embed column sum + sumsq. No intra-block reduce needed:
// each thread owns 4 columns (float4) across its block's 32 rows.
__global__ __launch_bounds__(256) void stream_kernel(const float* __restrict__ input,
                                                     const float* __restrict__ embed,
                                                     float* __restrict__ pSign,
                                                     float* __restrict__ pS,
                                                     float* __restrict__ pQ) {
    const int b = blockIdx.x;
    const int col = threadIdx.x * 4;

    if (b < IN_BLOCKS) {
        // sign-count over rows 32b .. 32b+31 of input
        const size_t r0 = (size_t)b * ROWS;
        float4 s = make_float4(0.f, 0.f, 0.f, 0.f);
#pragma unroll 4
        for (int r = 0; r < ROWS; ++r) {
            float4 v = *reinterpret_cast<const float4*>(input + (r0 + r) * D + col);
            s.x += (v.x > 0.f ? 1.f : 0.f) - (v.x < 0.f ? 1.f : 0.f);
            s.y += (v.y > 0.f ? 1.f : 0.f) - (v.y < 0.f ? 1.f : 0.f);
            s.z += (v.z > 0.f ? 1.f : 0.f) - (v.z < 0.f ? 1.f : 0.f);
            s.w += (v.w > 0.f ? 1.f : 0.f) - (v.w < 0.f ? 1.f : 0.f);
        }
        *reinterpret_cast<float4*>(pSign + (size_t)b * D + col) = s;
    } else {
        const int e = b - IN_BLOCKS;
        const size_t r0 = (size_t)e * ROWS;
        float4 s = make_float4(0.f, 0.f, 0.f, 0.f);
        float4 q = make_float4(0.f, 0.f, 0.f, 0.f);
#pragma unroll 4
        for (int r = 0; r < ROWS; ++r) {
            float4 v = *reinterpret_cast<const float4*>(embed + (r0 + r) * D + col);
            s.x += v.x; s.y += v.y; s.z += v.z; s.w += v.w;
            q.x += v.x * v.x; q.y += v.y * v.y; q.z += v.z * v.z; q.w += v.w * v.w;
        }
        *reinterpret_cast<float4*>(pS + (size_t)e * D + col) = s;
        *reinterpret_cast<float4*>(pQ + (size_t)e * D + col) = q;
    }
}

// K2: per-column reduce + contribution. Block handles 16 consecutive columns.
// Thread t: g = t/16 (source-block stripe), c = t%16 (column). Reads are
// 64B-coalesced: 16 consecutive 4B addrs per 16-lane group.
__global__ __launch_bounds__(256) void reduce_kernel(const float* __restrict__ pSign,
                                                     const float* __restrict__ pS,
                                                     const float* __restrict__ pQ,
                                                     double* __restrict__ blockRes) {
    const int t = threadIdx.x;
    const int g = t >> 4;        // 0..15
    const int c = t & 15;        // 0..15
    const int d = blockIdx.x * 16 + c;

    double sgn = 0.0, se = 0.0, qq = 0.0;
    for (int bb = g; bb < IN_BLOCKS; bb += 16)
        sgn += (double)pSign[(size_t)bb * D + d];
    for (int bb = g; bb < EM_BLOCKS; bb += 16) {
        se += (double)pS[(size_t)bb * D + d];
        qq += (double)pQ[(size_t)bb * D + d];
    }

    // reduce over g within each wave (lanes differing by 16 and 32)
    sgn += __shfl_xor(sgn, 16); sgn += __shfl_xor(sgn, 32);
    se  += __shfl_xor(se, 16);  se  += __shfl_xor(se, 32);
    qq  += __shfl_xor(qq, 16);  qq  += __shfl_xor(qq, 32);

    __shared__ double ls[3][4][16];
    const int wid = t >> 6;
    const int lane = t & 63;
    if (lane < 16) { ls[0][wid][lane] = sgn; ls[1][wid][lane] = se; ls[2][wid][lane] = qq; }
    __syncthreads();

    __shared__ double contrib[16];
    if (t < 16) {
        double S = ls[0][0][t] + ls[0][1][t] + ls[0][2][t] + ls[0][3][t];
        double E = ls[1][0][t] + ls[1][1][t] + ls[1][2][t] + ls[1][3][t];
        double Q = ls[2][0][t] + ls[2][1][t] + ls[2][2][t] + ls[2][3][t];
        double n2 = sqrt(Q);
        // coef = s_e / (sqrt(M) * max(n2, eps));  term sum = coef * S
        contrib[t] = (E / (90.50966799187809 * fmax(n2, EPS))) * S;
    }
    __syncthreads();
    if (t == 0) {
        double acc = 0.0;
        for (int i = 0; i < 16; ++i) acc += contrib[i];   // fixed order
        blockRes[blockIdx.x] = acc;
    }
}

// K3: final 64 -> scalar
__global__ void final_kernel(const double* __restrict__ blockRes,
                             float* __restrict__ out) {
    double acc = (threadIdx.x < RED_BLOCKS) ? blockRes[threadIdx.x] : 0.0;
    for (int off = 32; off > 0; off >>= 1) acc += __shfl_down(acc, off);
    if (threadIdx.x == 0) out[0] = (float)acc;
}

extern "C" void kernel_launch(void* const* d_in, const int* in_sizes, int n_in,
                              void* d_out, int out_size, void* d_ws, size_t ws_size,
                              hipStream_t stream) {
    const float* input = (const float*)d_in[0];   // [N, D]
    const float* embed = (const float*)d_in[1];   // [M, D]
    float* out = (float*)d_out;

    char* ws = (char*)d_ws;
    float* pSign = (float*)ws;                                        // 512*1024 f32
    float* pS = pSign + (size_t)IN_BLOCKS * D;                        // 256*1024 f32
    float* pQ = pS + (size_t)EM_BLOCKS * D;                           // 256*1024 f32
    double* blockRes = (double*)(pQ + (size_t)EM_BLOCKS * D);         // 64 f64

    stream_kernel<<<IN_BLOCKS + EM_BLOCKS, 256, 0, stream>>>(input, embed, pSign, pS, pQ);
    reduce_kernel<<<RED_BLOCKS, 256, 0, stream>>>(pSign, pS, pQ, blockRes);
    final_kernel<<<1, 64, 0, stream>>>(blockRes, out);
}